// Round 11
// baseline (231.990 us; speedup 1.0000x reference)
//
#include <hip/hip_runtime.h>
#include <hip/hip_bf16.h>
#include <stdint.h>

#define N_IMG 8
#define K_INS 16
#define CCH   64
#define SB    256    // pixel chunks: chunk = HW/SB = 256 px
#define PXC   256    // norm pixel chunk
#define EPSV  1e-5f

typedef float vfloat4 __attribute__((ext_vector_type(4)));
typedef short bf16x8 __attribute__((ext_vector_type(8)));
typedef float f32x4 __attribute__((ext_vector_type(4)));

// workspace layout (bytes):
//   [0, 16777216)            float2 P[N][4][SB][256]  partial (sum,sumsq), inner = c_local*16+k
//   [16777216, 16908288)     float  P2[N][SB][16]     partial counts per k
//   [16908288, 16973824)     float2 scsh[N][C][K]     (scale, shift)
// all fully written each call; no atomics anywhere -> deterministic, no memset.
#define P_OFF    0
#define P2_OFF   16777216
#define SCSH_OFF 16908288

__device__ __forceinline__ short bf16_bits(float v) {
    __hip_bfloat16 h = __float2bfloat16(v);
    union { __hip_bfloat16 h; short s; } u;
    u.h = h;
    return u.s;
}

__global__ __launch_bounds__(256) void stats_kernel(const float* __restrict__ x,
                                                    const int* __restrict__ ids,
                                                    float2* __restrict__ P,
                                                    float* __restrict__ P2, int HW,
                                                    int reps) {
    // grid: (N, SB). 4 waves = 4 c-blocks over the SAME 256-pixel chunk.
    // PROBE: reps(runtime)x identical idempotent passes -> surfaces in top-5
    // with counters; timing arithmetic unchanged per-pass.
    const int n = blockIdx.x;
    const int sb = blockIdx.y;
    const int t = threadIdx.x;
    const int wave = t >> 6;
    const int lane = t & 63;
    const int row = lane & 15;
    const int kg = lane >> 4;

    const int chunk = HW / SB;  // 256
    const float* xrow = x + (size_t)(n * CCH + wave * 16 + row) * HW + sb * chunk;
    const int* idp = ids + (size_t)n * HW + sb * chunk;

    bf16x8 ones;
#pragma unroll
    for (int j = 0; j < 8; ++j) ones[j] = (short)0x3F80;  // bf16 1.0

    for (int rep = 0; rep < reps; ++rep) {
        asm volatile("" ::: "memory");  // forbid load CSE across reps
        f32x4 accS = {0.f, 0.f, 0.f, 0.f};
        f32x4 accQ = {0.f, 0.f, 0.f, 0.f};
        f32x4 accC = {0.f, 0.f, 0.f, 0.f};

#pragma unroll
        for (int s = 0; s < 8; ++s) {
            const int p = s * 32 + kg * 8;
            float4 xa = *(const float4*)(xrow + p);
            float4 xb = *(const float4*)(xrow + p + 4);
            int4 ia = *(const int4*)(idp + p);
            int4 ib = *(const int4*)(idp + p + 4);
            float xs[8] = {xa.x, xa.y, xa.z, xa.w, xb.x, xb.y, xb.z, xb.w};
            int iv[8] = {ia.x, ia.y, ia.z, ia.w, ib.x, ib.y, ib.z, ib.w};
            bf16x8 ax, aq, mk;
#pragma unroll
            for (int j = 0; j < 8; ++j) {
                ax[j] = bf16_bits(xs[j]);
                aq[j] = bf16_bits(xs[j] * xs[j]);
                mk[j] = (iv[j] == row) ? (short)0x3F80 : (short)0;
            }
            accS = __builtin_amdgcn_mfma_f32_16x16x32_bf16(ax, mk, accS, 0, 0, 0);
            accQ = __builtin_amdgcn_mfma_f32_16x16x32_bf16(aq, mk, accQ, 0, 0, 0);
            accC = __builtin_amdgcn_mfma_f32_16x16x32_bf16(ones, mk, accC, 0, 0, 0);
        }

        float2* Pb = P + (size_t)((n * 4 + wave) * SB + sb) * 256;
#pragma unroll
        for (int r = 0; r < 4; ++r) {
            Pb[(kg * 4 + r) * 16 + row] = make_float2(accS[r], accQ[r]);
        }
        if (t < 16) P2[((size_t)n * SB + sb) * 16 + t] = accC[0];
    }
}

__global__ __launch_bounds__(256) void finalize_kernel(const float2* __restrict__ P,
                                                       const float* __restrict__ P2,
                                                       const float* __restrict__ gamma,
                                                       const float* __restrict__ beta,
                                                       float2* __restrict__ scsh) {
    const int cb = blockIdx.x;
    const int n = blockIdx.y;
    const int t = threadIdx.x;

    __shared__ float csh[16][17];
    const float* P2n = P2 + (size_t)n * SB * 16;
    float cc = 0.f;
#pragma unroll 4
    for (int i = 0; i < 16; ++i) cc += P2n[((t >> 4) * 16 + i) * 16 + (t & 15)];
    csh[t >> 4][t & 15] = cc;

    const float2* Pb = P + (size_t)(n * 4 + cb) * SB * 256;
    float rs = 0.f, rq = 0.f;
#pragma unroll 16
    for (int sb = 0; sb < SB; ++sb) {
        float2 v = Pb[(size_t)sb * 256 + t];
        rs += v.x;
        rq += v.y;
    }
    __syncthreads();
    float cnt = 0.f;
#pragma unroll
    for (int i = 0; i < 16; ++i) cnt += csh[i][t & 15];

    const int c = cb * 16 + (t >> 4);
    const int k = t & 15;
    float denom = fmaxf(cnt, 1.0f);
    float mean = rs / denom;
    float var = rq / denom - mean * mean;
    float r = rsqrtf(var + EPSV);
    float sc = r * gamma[c];
    float sh = beta[c] - mean * sc;
    scsh[((size_t)n * CCH + c) * K_INS + k] = make_float2(sc, sh);
}

__global__ __launch_bounds__(256) void norm_kernel(const float* __restrict__ x,
                                                   const int* __restrict__ ids,
                                                   const float2* __restrict__ scsh,
                                                   float* __restrict__ out, int HW,
                                                   int reps) {
    // grid: (HW/PXC, N). Block owns 256 pixels x ALL 64 channels.
    // PROBE: reps(runtime)x idempotent passes; PLAIN stores (nt removed: A/B).
    const int sb = blockIdx.x;
    const int n = blockIdx.y;
    const int t = threadIdx.x;
    const int lane = t & 63;
    const int wave = t >> 6;
    const int px0 = sb * PXC;

    int4 myid = *(const int4*)(ids + (size_t)n * HW + px0 + lane * 4);

    __shared__ float2 ls[CCH * K_INS];
    const float4* src = (const float4*)(scsh + (size_t)n * CCH * K_INS);
    ((float4*)ls)[t] = src[t];
    ((float4*)ls)[t + 256] = src[t + 256];
    __syncthreads();

    const int i0 = max(myid.x, 0), i1 = max(myid.y, 0);
    const int i2 = max(myid.z, 0), i3 = max(myid.w, 0);

    for (int rep = 0; rep < reps; ++rep) {
        asm volatile("" ::: "memory");  // forbid load CSE across reps
#pragma unroll 4
        for (int ci = 0; ci < 16; ++ci) {
            const int c = wave * 16 + ci;
            const float* xr = x + ((size_t)n * CCH + c) * HW + px0;
            float4 xv = *(const float4*)(xr + lane * 4);
            const float2* lc = ls + c * K_INS;
            float2 s0 = lc[i0], s1 = lc[i1], s2 = lc[i2], s3 = lc[i3];
            vfloat4 o;
            o.x = (myid.x >= 0) ? fmaf(xv.x, s0.x, s0.y) : xv.x;
            o.y = (myid.y >= 0) ? fmaf(xv.y, s1.x, s1.y) : xv.y;
            o.z = (myid.z >= 0) ? fmaf(xv.z, s2.x, s2.y) : xv.z;
            o.w = (myid.w >= 0) ? fmaf(xv.w, s3.x, s3.y) : xv.w;
            *((vfloat4*)(out + ((size_t)n * CCH + c) * HW + px0) + lane) = o;
        }
    }
}

extern "C" void kernel_launch(void* const* d_in, const int* in_sizes, int n_in,
                              void* d_out, int out_size, void* d_ws, size_t ws_size,
                              hipStream_t stream) {
    const float* x = (const float*)d_in[0];
    const int* ids = (const int*)d_in[1];
    const float* gamma = (const float*)d_in[2];
    const float* beta = (const float*)d_in[3];
    float* out = (float*)d_out;

    const int HW = in_sizes[1] / N_IMG;  // 65536

    float2* P = (float2*)((char*)d_ws + P_OFF);
    float* P2 = (float*)((char*)d_ws + P2_OFF);
    float2* scsh = (float2*)((char*)d_ws + SCSH_OFF);

    // DIAGNOSIS ROUND: stats x4 and norm x3 (in-kernel reps, idempotent) so
    // both dispatches exceed the ~75us harness fills and surface in top-5
    // WITH counters. Norm additionally runs with plain (non-nt) stores as
    // the bundled fix candidate. Next round reverts reps to 1.
    stats_kernel<<<dim3(N_IMG, SB), 256, 0, stream>>>(x, ids, P, P2, HW, 4);
    finalize_kernel<<<dim3(4, N_IMG), 256, 0, stream>>>(P, P2, gamma, beta, scsh);
    norm_kernel<<<dim3(HW / PXC, N_IMG), 256, 0, stream>>>(x, ids, scsh, out, HW, 3);
}

// Round 12
// 91.822 us; speedup vs baseline: 2.5265x; 2.5265x over previous
//
#include <hip/hip_runtime.h>
#include <hip/hip_bf16.h>
#include <stdint.h>

#define N_IMG 8
#define K_INS 16
#define CCH   64
#define SB    256    // stats pixel chunks: chunk = HW/SB = 256 px
#define PXC   512    // norm pixel chunk (8 px per lane)
#define EPSV  1e-5f

typedef float vfloat4 __attribute__((ext_vector_type(4)));
typedef short bf16x8 __attribute__((ext_vector_type(8)));
typedef float f32x4 __attribute__((ext_vector_type(4)));

// workspace layout (bytes):
//   [0, 16777216)            float2 P[N][4][SB][256]  partial (sum,sumsq), inner = c_local*16+k
//   [16777216, 16908288)     float  P2[N][SB][16]     partial counts per k
//   [16908288, 16973824)     float2 scsh[N][C][K]     (scale, shift)
// all fully written each call; no atomics anywhere -> deterministic, no memset.
#define P_OFF    0
#define P2_OFF   16777216
#define SCSH_OFF 16908288

__device__ __forceinline__ short bf16_bits(float v) {
    __hip_bfloat16 h = __float2bfloat16(v);
    union { __hip_bfloat16 h; short s; } u;
    u.h = h;
    return u.s;
}

__global__ __launch_bounds__(256) void stats_kernel(const float* __restrict__ x,
                                                    const int* __restrict__ ids,
                                                    float2* __restrict__ P,
                                                    float* __restrict__ P2, int HW) {
    // grid: (N, SB). 4 waves = 4 c-blocks over the SAME 256-pixel chunk.
    //   S[c][k] += x[c][p]*mask[p][k]; Q += x^2*mask; Cnt += 1*mask (exact f32)
    // via mfma_f32_16x16x32_bf16. ~86% of its BW roofline (25us, r10 probe).
    const int n = blockIdx.x;
    const int sb = blockIdx.y;
    const int t = threadIdx.x;
    const int wave = t >> 6;
    const int lane = t & 63;
    const int row = lane & 15;
    const int kg = lane >> 4;

    const int chunk = HW / SB;  // 256
    const float* xrow = x + (size_t)(n * CCH + wave * 16 + row) * HW + sb * chunk;
    const int* idp = ids + (size_t)n * HW + sb * chunk;

    bf16x8 ones;
#pragma unroll
    for (int j = 0; j < 8; ++j) ones[j] = (short)0x3F80;  // bf16 1.0

    f32x4 accS = {0.f, 0.f, 0.f, 0.f};
    f32x4 accQ = {0.f, 0.f, 0.f, 0.f};
    f32x4 accC = {0.f, 0.f, 0.f, 0.f};

#pragma unroll
    for (int s = 0; s < 8; ++s) {
        const int p = s * 32 + kg * 8;
        float4 xa = *(const float4*)(xrow + p);
        float4 xb = *(const float4*)(xrow + p + 4);
        int4 ia = *(const int4*)(idp + p);
        int4 ib = *(const int4*)(idp + p + 4);
        float xs[8] = {xa.x, xa.y, xa.z, xa.w, xb.x, xb.y, xb.z, xb.w};
        int iv[8] = {ia.x, ia.y, ia.z, ia.w, ib.x, ib.y, ib.z, ib.w};
        bf16x8 ax, aq, mk;
#pragma unroll
        for (int j = 0; j < 8; ++j) {
            ax[j] = bf16_bits(xs[j]);
            aq[j] = bf16_bits(xs[j] * xs[j]);
            mk[j] = (iv[j] == row) ? (short)0x3F80 : (short)0;
        }
        accS = __builtin_amdgcn_mfma_f32_16x16x32_bf16(ax, mk, accS, 0, 0, 0);
        accQ = __builtin_amdgcn_mfma_f32_16x16x32_bf16(aq, mk, accQ, 0, 0, 0);
        accC = __builtin_amdgcn_mfma_f32_16x16x32_bf16(ones, mk, accC, 0, 0, 0);
    }

    float2* Pb = P + (size_t)((n * 4 + wave) * SB + sb) * 256;
#pragma unroll
    for (int r = 0; r < 4; ++r) {
        Pb[(kg * 4 + r) * 16 + row] = make_float2(accS[r], accQ[r]);
    }
    if (t < 16) P2[((size_t)n * SB + sb) * 16 + t] = accC[0];
}

__global__ __launch_bounds__(256) void finalize_kernel(const float2* __restrict__ P,
                                                       const float* __restrict__ P2,
                                                       const float* __restrict__ gamma,
                                                       const float* __restrict__ beta,
                                                       float2* __restrict__ scsh) {
    const int cb = blockIdx.x;
    const int n = blockIdx.y;
    const int t = threadIdx.x;

    __shared__ float csh[16][17];
    const float* P2n = P2 + (size_t)n * SB * 16;
    float cc = 0.f;
#pragma unroll 4
    for (int i = 0; i < 16; ++i) cc += P2n[((t >> 4) * 16 + i) * 16 + (t & 15)];
    csh[t >> 4][t & 15] = cc;

    const float2* Pb = P + (size_t)(n * 4 + cb) * SB * 256;
    float rs = 0.f, rq = 0.f;
#pragma unroll 16
    for (int sb = 0; sb < SB; ++sb) {
        float2 v = Pb[(size_t)sb * 256 + t];
        rs += v.x;
        rq += v.y;
    }
    __syncthreads();
    float cnt = 0.f;
#pragma unroll
    for (int i = 0; i < 16; ++i) cnt += csh[i][t & 15];

    const int c = cb * 16 + (t >> 4);
    const int k = t & 15;
    float denom = fmaxf(cnt, 1.0f);
    float mean = rs / denom;
    float var = rq / denom - mean * mean;
    float r = rsqrtf(var + EPSV);
    float sc = r * gamma[c];
    float sh = beta[c] - mean * sc;
    scsh[((size_t)n * CCH + c) * K_INS + k] = make_float2(sc, sh);
}

__global__ __launch_bounds__(256) void norm_kernel(const float* __restrict__ x,
                                                   const int* __restrict__ ids,
                                                   const float2* __restrict__ scsh,
                                                   float* __restrict__ out, int HW) {
    // grid: (HW/PXC = 128, N) = 1024 blocks. Block owns 512 pixels x all 64
    // channels; each wave covers its 16 channels over all 512 px, 8 px/lane
    // (2x float4 per c-iter -> doubled per-thread ILP vs r9). ids loaded once
    // per lane; full 8KB (c,k) table in LDS (<=16 distinct broadcast
    // addresses per gather -> conflict-free). Plain stores (nt measured
    // slower in r11: L2 write-back beats nt bypass).
    const int sb = blockIdx.x;
    const int n = blockIdx.y;
    const int t = threadIdx.x;
    const int lane = t & 63;
    const int wave = t >> 6;
    const int px0 = sb * PXC;

    const int* idbase = ids + (size_t)n * HW + px0 + lane * 8;
    int4 ida = *(const int4*)(idbase);
    int4 idb = *(const int4*)(idbase + 4);

    __shared__ float2 ls[CCH * K_INS];
    const float4* src = (const float4*)(scsh + (size_t)n * CCH * K_INS);
    ((float4*)ls)[t] = src[t];
    ((float4*)ls)[t + 256] = src[t + 256];
    __syncthreads();

    const int a0 = max(ida.x, 0), a1 = max(ida.y, 0), a2 = max(ida.z, 0), a3 = max(ida.w, 0);
    const int b0 = max(idb.x, 0), b1 = max(idb.y, 0), b2 = max(idb.z, 0), b3 = max(idb.w, 0);

#pragma unroll
    for (int ci = 0; ci < 16; ++ci) {
        const int c = wave * 16 + ci;
        const float* xr = x + ((size_t)n * CCH + c) * HW + px0 + lane * 8;
        float4 xa = *(const float4*)(xr);
        float4 xb = *(const float4*)(xr + 4);
        const float2* lc = ls + c * K_INS;
        float2 sa0 = lc[a0], sa1 = lc[a1], sa2 = lc[a2], sa3 = lc[a3];
        float2 sb0 = lc[b0], sb1 = lc[b1], sb2 = lc[b2], sb3 = lc[b3];
        vfloat4 oa, ob;
        oa.x = (ida.x >= 0) ? fmaf(xa.x, sa0.x, sa0.y) : xa.x;
        oa.y = (ida.y >= 0) ? fmaf(xa.y, sa1.x, sa1.y) : xa.y;
        oa.z = (ida.z >= 0) ? fmaf(xa.z, sa2.x, sa2.y) : xa.z;
        oa.w = (ida.w >= 0) ? fmaf(xa.w, sa3.x, sa3.y) : xa.w;
        ob.x = (idb.x >= 0) ? fmaf(xb.x, sb0.x, sb0.y) : xb.x;
        ob.y = (idb.y >= 0) ? fmaf(xb.y, sb1.x, sb1.y) : xb.y;
        ob.z = (idb.z >= 0) ? fmaf(xb.z, sb2.x, sb2.y) : xb.z;
        ob.w = (idb.w >= 0) ? fmaf(xb.w, sb3.x, sb3.y) : xb.w;
        float* orow = out + ((size_t)n * CCH + c) * HW + px0 + lane * 8;
        *(vfloat4*)(orow) = oa;
        *(vfloat4*)(orow + 4) = ob;
    }
}

extern "C" void kernel_launch(void* const* d_in, const int* in_sizes, int n_in,
                              void* d_out, int out_size, void* d_ws, size_t ws_size,
                              hipStream_t stream) {
    const float* x = (const float*)d_in[0];
    const int* ids = (const int*)d_in[1];
    const float* gamma = (const float*)d_in[2];
    const float* beta = (const float*)d_in[3];
    float* out = (float*)d_out;

    const int HW = in_sizes[1] / N_IMG;  // 65536

    float2* P = (float2*)((char*)d_ws + P_OFF);
    float* P2 = (float*)((char*)d_ws + P2_OFF);
    float2* scsh = (float2*)((char*)d_ws + SCSH_OFF);

    stats_kernel<<<dim3(N_IMG, SB), 256, 0, stream>>>(x, ids, P, P2, HW);
    finalize_kernel<<<dim3(4, N_IMG), 256, 0, stream>>>(P, P2, gamma, beta, scsh);
    norm_kernel<<<dim3(HW / PXC, N_IMG), 256, 0, stream>>>(x, ids, scsh, out, HW);
}

// Round 13
// 90.858 us; speedup vs baseline: 2.5533x; 1.0106x over previous
//
#include <hip/hip_runtime.h>
#include <hip/hip_bf16.h>
#include <stdint.h>

#define N_IMG 8
#define K_INS 16
#define CCH   64
#define SB    256    // stats pixel chunks: chunk = HW/SB = 256 px
#define PXC   256    // norm pixel chunk (4 px per lane, grid 2048 -> 32 waves/CU)
#define EPSV  1e-5f

typedef float vfloat4 __attribute__((ext_vector_type(4)));
typedef short bf16x8 __attribute__((ext_vector_type(8)));
typedef float f32x4 __attribute__((ext_vector_type(4)));

// workspace layout (bytes):
//   [0, 16777216)            float2 P[N][4][SB][256]  partial (sum,sumsq), inner = c_local*16+k
//   [16777216, 16908288)     float  P2[N][SB][16]     partial counts per k
//   [16908288, 16973824)     float2 scsh[N][C][K]     (scale, shift)
// all fully written each call; no atomics anywhere -> deterministic, no memset.
#define P_OFF    0
#define P2_OFF   16777216
#define SCSH_OFF 16908288

__device__ __forceinline__ short bf16_bits(float v) {
    __hip_bfloat16 h = __float2bfloat16(v);
    union { __hip_bfloat16 h; short s; } u;
    u.h = h;
    return u.s;
}

__global__ __launch_bounds__(256) void stats_kernel(const float* __restrict__ x,
                                                    const int* __restrict__ ids,
                                                    float2* __restrict__ P,
                                                    float* __restrict__ P2, int HW) {
    // grid: (N, SB). 4 waves = 4 c-blocks over the SAME 256-pixel chunk.
    //   S[c][k] += x[c][p]*mask[p][k]; Q += x^2*mask; Cnt += 1*mask (exact f32)
    // via mfma_f32_16x16x32_bf16. 25us vs 21.6us BW floor (r10 probe).
    const int n = blockIdx.x;
    const int sb = blockIdx.y;
    const int t = threadIdx.x;
    const int wave = t >> 6;
    const int lane = t & 63;
    const int row = lane & 15;
    const int kg = lane >> 4;

    const int chunk = HW / SB;  // 256
    const float* xrow = x + (size_t)(n * CCH + wave * 16 + row) * HW + sb * chunk;
    const int* idp = ids + (size_t)n * HW + sb * chunk;

    bf16x8 ones;
#pragma unroll
    for (int j = 0; j < 8; ++j) ones[j] = (short)0x3F80;  // bf16 1.0

    f32x4 accS = {0.f, 0.f, 0.f, 0.f};
    f32x4 accQ = {0.f, 0.f, 0.f, 0.f};
    f32x4 accC = {0.f, 0.f, 0.f, 0.f};

#pragma unroll
    for (int s = 0; s < 8; ++s) {
        const int p = s * 32 + kg * 8;
        float4 xa = *(const float4*)(xrow + p);
        float4 xb = *(const float4*)(xrow + p + 4);
        int4 ia = *(const int4*)(idp + p);
        int4 ib = *(const int4*)(idp + p + 4);
        float xs[8] = {xa.x, xa.y, xa.z, xa.w, xb.x, xb.y, xb.z, xb.w};
        int iv[8] = {ia.x, ia.y, ia.z, ia.w, ib.x, ib.y, ib.z, ib.w};
        bf16x8 ax, aq, mk;
#pragma unroll
        for (int j = 0; j < 8; ++j) {
            ax[j] = bf16_bits(xs[j]);
            aq[j] = bf16_bits(xs[j] * xs[j]);
            mk[j] = (iv[j] == row) ? (short)0x3F80 : (short)0;
        }
        accS = __builtin_amdgcn_mfma_f32_16x16x32_bf16(ax, mk, accS, 0, 0, 0);
        accQ = __builtin_amdgcn_mfma_f32_16x16x32_bf16(aq, mk, accQ, 0, 0, 0);
        accC = __builtin_amdgcn_mfma_f32_16x16x32_bf16(ones, mk, accC, 0, 0, 0);
    }

    float2* Pb = P + (size_t)((n * 4 + wave) * SB + sb) * 256;
#pragma unroll
    for (int r = 0; r < 4; ++r) {
        Pb[(kg * 4 + r) * 16 + row] = make_float2(accS[r], accQ[r]);
    }
    if (t < 16) P2[((size_t)n * SB + sb) * 16 + t] = accC[0];
}

__global__ __launch_bounds__(256) void finalize_kernel(const float2* __restrict__ P,
                                                       const float* __restrict__ P2,
                                                       const float* __restrict__ gamma,
                                                       const float* __restrict__ beta,
                                                       float2* __restrict__ scsh) {
    const int cb = blockIdx.x;
    const int n = blockIdx.y;
    const int t = threadIdx.x;

    __shared__ float csh[16][17];
    const float* P2n = P2 + (size_t)n * SB * 16;
    float cc = 0.f;
#pragma unroll 4
    for (int i = 0; i < 16; ++i) cc += P2n[((t >> 4) * 16 + i) * 16 + (t & 15)];
    csh[t >> 4][t & 15] = cc;

    const float2* Pb = P + (size_t)(n * 4 + cb) * SB * 256;
    float rs = 0.f, rq = 0.f;
#pragma unroll 16
    for (int sb = 0; sb < SB; ++sb) {
        float2 v = Pb[(size_t)sb * 256 + t];
        rs += v.x;
        rq += v.y;
    }
    __syncthreads();
    float cnt = 0.f;
#pragma unroll
    for (int i = 0; i < 16; ++i) cnt += csh[i][t & 15];

    const int c = cb * 16 + (t >> 4);
    const int k = t & 15;
    float denom = fmaxf(cnt, 1.0f);
    float mean = rs / denom;
    float var = rq / denom - mean * mean;
    float r = rsqrtf(var + EPSV);
    float sc = r * gamma[c];
    float sh = beta[c] - mean * sc;
    scsh[((size_t)n * CCH + c) * K_INS + k] = make_float2(sc, sh);
}

__global__ __launch_bounds__(256) void norm_kernel(const float* __restrict__ x,
                                                   const int* __restrict__ ids,
                                                   const float2* __restrict__ scsh,
                                                   float* __restrict__ out, int HW) {
    // grid: (HW/PXC = 256, N) = 2048 blocks -> 8 blocks/CU, 32 waves/CU (max
    // TLP; r12 showed halving this costs ~14us). Block owns 256 px x all 64
    // channels; ids loaded once per lane (4 px); 8KB (c,k) table in LDS
    // (<=16 distinct broadcast addresses per gather -> conflict-free).
    // PLAIN stores: r11 A/B measured nt-store 10us slower (L2 write-back
    // beats nt HBM bypass).
    const int sb = blockIdx.x;
    const int n = blockIdx.y;
    const int t = threadIdx.x;
    const int lane = t & 63;
    const int wave = t >> 6;
    const int px0 = sb * PXC;

    int4 myid = *(const int4*)(ids + (size_t)n * HW + px0 + lane * 4);

    __shared__ float2 ls[CCH * K_INS];
    const float4* src = (const float4*)(scsh + (size_t)n * CCH * K_INS);
    ((float4*)ls)[t] = src[t];
    ((float4*)ls)[t + 256] = src[t + 256];
    __syncthreads();

    const int i0 = max(myid.x, 0), i1 = max(myid.y, 0);
    const int i2 = max(myid.z, 0), i3 = max(myid.w, 0);

#pragma unroll 4
    for (int ci = 0; ci < 16; ++ci) {
        const int c = wave * 16 + ci;
        const float* xr = x + ((size_t)n * CCH + c) * HW + px0;
        float4 xv = *(const float4*)(xr + lane * 4);
        const float2* lc = ls + c * K_INS;
        float2 s0 = lc[i0], s1 = lc[i1], s2 = lc[i2], s3 = lc[i3];
        vfloat4 o;
        o.x = (myid.x >= 0) ? fmaf(xv.x, s0.x, s0.y) : xv.x;
        o.y = (myid.y >= 0) ? fmaf(xv.y, s1.x, s1.y) : xv.y;
        o.z = (myid.z >= 0) ? fmaf(xv.z, s2.x, s2.y) : xv.z;
        o.w = (myid.w >= 0) ? fmaf(xv.w, s3.x, s3.y) : xv.w;
        *((vfloat4*)(out + ((size_t)n * CCH + c) * HW + px0) + lane) = o;
    }
}

extern "C" void kernel_launch(void* const* d_in, const int* in_sizes, int n_in,
                              void* d_out, int out_size, void* d_ws, size_t ws_size,
                              hipStream_t stream) {
    const float* x = (const float*)d_in[0];
    const int* ids = (const int*)d_in[1];
    const float* gamma = (const float*)d_in[2];
    const float* beta = (const float*)d_in[3];
    float* out = (float*)d_out;

    const int HW = in_sizes[1] / N_IMG;  // 65536

    float2* P = (float2*)((char*)d_ws + P_OFF);
    float* P2 = (float*)((char*)d_ws + P2_OFF);
    float2* scsh = (float2*)((char*)d_ws + SCSH_OFF);

    stats_kernel<<<dim3(N_IMG, SB), 256, 0, stream>>>(x, ids, P, P2, HW);
    finalize_kernel<<<dim3(4, N_IMG), 256, 0, stream>>>(P, P2, gamma, beta, scsh);
    norm_kernel<<<dim3(HW / PXC, N_IMG), 256, 0, stream>>>(x, ids, scsh, out, HW);
}